// Round 1
// baseline (162.288 us; speedup 1.0000x reference)
//
#include <hip/hip_runtime.h>
#include <stdint.h>

// ---- types ----
typedef __attribute__((ext_vector_type(4))) float   f4;
typedef __attribute__((ext_vector_type(8))) short   short8;   // 8 x bf16 (MFMA A/B frag)
typedef __attribute__((ext_vector_type(4))) float   floatx4;  // MFMA C/D frag
typedef __attribute__((ext_vector_type(4))) unsigned int u32x4;

#define LN2F 0.6931471805599453f

// Problem constants
#define BB 65536
#define SS 512
#define DD 100
// K padded to 128 (4 k-steps of 32 for mfma 16x16x32 bf16)

__device__ __forceinline__ unsigned short f2bf(float f) {
  union { float f; unsigned int u; } v; v.f = f;
  unsigned int u = v.u;
  u += 0x7fffu + ((u >> 16) & 1u);   // RNE
  return (unsigned short)(u >> 16);
}
__device__ __forceinline__ float bf2f(short s) {
  union { float f; unsigned int u; } v;
  v.u = ((unsigned int)(unsigned short)s) << 16;
  return v.f;
}
__device__ __forceinline__ u32x4 pack8(f4 a, f4 b) {
  u32x4 r;
  r.x = (unsigned int)f2bf(a[0]) | ((unsigned int)f2bf(a[1]) << 16);
  r.y = (unsigned int)f2bf(a[2]) | ((unsigned int)f2bf(a[3]) << 16);
  r.z = (unsigned int)f2bf(b[0]) | ((unsigned int)f2bf(b[1]) << 16);
  r.w = (unsigned int)f2bf(b[2]) | ((unsigned int)f2bf(b[3]) << 16);
  return r;
}
// numerically stable softplus(x) = -log_sigmoid(-x) ... wait: softplus(x) = log(1+e^x)
__device__ __forceinline__ float softplus_full(float x) {
  return fmaxf(x, 0.f) + log1pf(expf(-fabsf(x)));
}

// ---------------------------------------------------------------------------
// Kernel 1: gather + convert neg rows into MFMA B-fragment tiled layout in ws.
// Layout: 16B unit index = (sgroup*4 + kstep)*64 + (s&15) + 16*kquad
//   where sgroup = s>>4, kstep = k>>5, kquad = (k>>3)&3 ; 8 bf16 per unit.
// K in [100,128) zero-padded.
// ---------------------------------------------------------------------------
__global__ __launch_bounds__(256) void negprep_k(
    const float* __restrict__ tail_table, const int* __restrict__ neg_idx,
    u32x4* __restrict__ nws) {
  int tid = blockIdx.x * 256 + threadIdx.x;          // 32 blocks -> 8192 threads
  int s = tid >> 4, kg = tid & 15, k0 = kg * 8;      // 16 threads per s-row
  int nrow = neg_idx[s];
  const float* np = tail_table + (size_t)nrow * DD;  // rows are 400B = 16B aligned
  f4 a = {0.f,0.f,0.f,0.f}, b = {0.f,0.f,0.f,0.f};
  if (kg < 12)       { a = *(const f4*)(np + k0); b = *(const f4*)(np + k0 + 4); }
  else if (kg == 12) { a = *(const f4*)(np + 96); }   // k 96..99 valid, 100..103 pad
  nws[((s >> 4) * 4 + (kg >> 2)) * 64 + (s & 15) + 16 * (kg & 3)] = pack8(a, b);
}

// ---------------------------------------------------------------------------
// Kernel 2: main fused kernel. Block = 256 thr (4 waves) handles 64 b-rows x all 512 s.
//   stage1: gather ex = head[h_idx]+rel into LDS A-frag layout (bf16, K->128 pad)
//   pos   : each wave does 16 rows' pos loss (fp32-from-bf16 ex dot tail row)
//   neg   : each wave: 8 n-groups; B-frags via coalesced global loads from nws (L2-hot)
//           MFMA 16x16x32 bf16; epilogue = bias add + guarded softplus sum
// ---------------------------------------------------------------------------
__global__ __launch_bounds__(256, 2) void keg_main(
    const float* __restrict__ head_table, const float* __restrict__ tail_table,
    const float* __restrict__ rel_vec,   const float* __restrict__ rel_bias,
    const int* __restrict__ head_idx,    const int* __restrict__ tail_idx,
    const u32x4* __restrict__ nws,       float* __restrict__ partials) {
  __shared__ u32x4 exA4[1024];   // 64 rows x 128 k, A-frag tiled: 16KB
  __shared__ float bias_s[64];
  __shared__ float red[4];

  const int t = threadIdx.x;
  const int kg = t & 15, k0 = kg * 8, rid = t >> 4;
  const int bbase = blockIdx.x * 64;

  // ---- stage 1: gather ex into LDS (A-fragment layout), stash bias ----
  #pragma unroll
  for (int p = 0; p < 4; ++p) {
    int r  = p * 16 + rid;            // local row 0..63
    int gb = bbase + r;
    int hrow = head_idx[gb];
    const float* hp = head_table + (size_t)hrow * DD;
    f4 a = {0,0,0,0}, b = {0,0,0,0}, ra = {0,0,0,0}, rb = {0,0,0,0};
    if (kg < 12) {
      a  = *(const f4*)(hp + k0);       b  = *(const f4*)(hp + k0 + 4);
      ra = *(const f4*)(rel_vec + k0);  rb = *(const f4*)(rel_vec + k0 + 4);
    } else if (kg == 12) {
      a  = *(const f4*)(hp + 96);       ra = *(const f4*)(rel_vec + 96);
    }
    f4 e0 = a + ra, e1 = b + rb;
    // A-frag position: group g=p, lane = rid + 16*kquad, kstep = kg>>2
    exA4[(p * 4 + (kg >> 2)) * 64 + rid + 16 * (kg & 3)] = pack8(e0, e1);
    if (kg == 0) bias_s[r] = rel_bias[tail_idx[gb]];
  }
  __syncthreads();

  const int w = t >> 6, lane = t & 63;
  const int m15 = lane & 15, quad = lane >> 4;
  const short8* exAs = (const short8*)exA4;

  // ---- pos part: wave w handles rows w*16 .. w*16+15 ----
  float pos_acc = 0.f;
  {
    int rloc = w * 16 + m15;
    int gb = bbase + rloc;
    int trow = tail_idx[gb];
    const float* tp = tail_table + (size_t)trow * DD;
    float pdot = 0.f;
    #pragma unroll
    for (int ks = 0; ks < 4; ++ks) {
      short8 ev = exAs[(w * 4 + ks) * 64 + lane];  // row m15, k = ks*32+quad*8..+7
      int kk = ks * 32 + quad * 8;
      f4 ta = {0,0,0,0}, tb = {0,0,0,0};
      if (kk < 96)       { ta = *(const f4*)(tp + kk); tb = *(const f4*)(tp + kk + 4); }
      else if (kk == 96) { ta = *(const f4*)(tp + 96); }
      pdot += bf2f(ev[0])*ta[0] + bf2f(ev[1])*ta[1] + bf2f(ev[2])*ta[2] + bf2f(ev[3])*ta[3];
      pdot += bf2f(ev[4])*tb[0] + bf2f(ev[5])*tb[1] + bf2f(ev[6])*tb[2] + bf2f(ev[7])*tb[3];
    }
    pdot += __shfl_xor(pdot, 16);
    pdot += __shfl_xor(pdot, 32);   // lanes {l, l^16, l^32, l^48} all hold full dot
    if (lane < 16) {
      float logit = pdot + bias_s[rloc];
      pos_acc = softplus_full(-logit);   // -log_sigmoid(logit)
    }
  }

  // ---- neg part ----
  short8 afr[4][4];
  #pragma unroll
  for (int mf = 0; mf < 4; ++mf)
    #pragma unroll
    for (int ks = 0; ks < 4; ++ks)
      afr[mf][ks] = exAs[(mf * 4 + ks) * 64 + lane];

  float biasr[4][4];   // bias for C rows: m = mf*16 + quad*4 + r
  #pragma unroll
  for (int mf = 0; mf < 4; ++mf)
    #pragma unroll
    for (int r2 = 0; r2 < 4; ++r2)
      biasr[mf][r2] = bias_s[mf * 16 + quad * 4 + r2];

  const short8* nfr = (const short8*)nws;
  float nacc = 0.f;
  for (int ng = w * 8; ng < w * 8 + 8; ++ng) {   // wave w: s-groups w*8..w*8+7
    short8 bfr[4];
    #pragma unroll
    for (int ks = 0; ks < 4; ++ks)
      bfr[ks] = nfr[(ng * 4 + ks) * 64 + lane];  // coalesced 1KB/wave, L2-hot
    floatx4 acc[4];
    #pragma unroll
    for (int mf = 0; mf < 4; ++mf) { floatx4 z = {0.f,0.f,0.f,0.f}; acc[mf] = z; }
    #pragma unroll
    for (int ks = 0; ks < 4; ++ks)
      #pragma unroll
      for (int mf = 0; mf < 4; ++mf)
        acc[mf] = __builtin_amdgcn_mfma_f32_16x16x32_bf16(afr[mf][ks], bfr[ks], acc[mf], 0, 0, 0);
    // epilogue: logits = acc + bias[b]; sum softplus
    float vmax = 0.f;
    #pragma unroll
    for (int mf = 0; mf < 4; ++mf)
      #pragma unroll
      for (int r2 = 0; r2 < 4; ++r2) {
        float x = acc[mf][r2] + biasr[mf][r2];
        acc[mf][r2] = x;
        vmax = fmaxf(vmax, fabsf(x));
      }
    if (__ballot(vmax < 0.03f) == ~0ULL) {
      // deg-2 Taylor: softplus(x) = ln2 + x/2 + x^2/8, |err| < 5e-9 for |x|<0.03
      float s2 = 0.f;
      #pragma unroll
      for (int mf = 0; mf < 4; ++mf)
        #pragma unroll
        for (int r2 = 0; r2 < 4; ++r2) {
          float x = acc[mf][r2];
          s2 = fmaf(x, fmaf(x, 0.125f, 0.5f), s2);
        }
      nacc += s2 + 16.f * LN2F;
    } else {
      #pragma unroll
      for (int mf = 0; mf < 4; ++mf)
        #pragma unroll
        for (int r2 = 0; r2 < 4; ++r2)
          nacc += softplus_full(acc[mf][r2]);
    }
  }

  // ---- block reduce -> partial ----
  float tot = nacc + pos_acc;
  #pragma unroll
  for (int off = 32; off; off >>= 1) tot += __shfl_down(tot, off);
  if (lane == 0) red[w] = tot;
  __syncthreads();
  if (t == 0) partials[blockIdx.x] = red[0] + red[1] + red[2] + red[3];
}

// ---------------------------------------------------------------------------
// Kernel 3: final reduction of 1024 block partials -> mean
// ---------------------------------------------------------------------------
__global__ __launch_bounds__(256) void reduce_k(const float* __restrict__ partials,
                                               float* __restrict__ out) {
  int t = threadIdx.x;
  double s = 0.0;
  for (int i = t; i < 1024; i += 256) s += (double)partials[i];
  #pragma unroll
  for (int off = 32; off; off >>= 1) s += __shfl_down(s, off);
  __shared__ double sred[4];
  if ((t & 63) == 0) sred[t >> 6] = s;
  __syncthreads();
  if (t == 0) out[0] = (float)((sred[0] + sred[1] + sred[2] + sred[3]) / (double)BB);
}

extern "C" void kernel_launch(void* const* d_in, const int* in_sizes, int n_in,
                              void* d_out, int out_size, void* d_ws, size_t ws_size,
                              hipStream_t stream) {
  const float* head_table = (const float*)d_in[0];
  const float* tail_table = (const float*)d_in[1];
  const float* rel_vec    = (const float*)d_in[2];
  const float* rel_bias   = (const float*)d_in[3];
  const int*   head_idx   = (const int*)d_in[4];
  const int*   tail_idx   = (const int*)d_in[5];
  const int*   neg_idx    = (const int*)d_in[6];
  float* out = (float*)d_out;

  char* ws = (char*)d_ws;
  u32x4* nws      = (u32x4*)ws;                 // 512 x 128 bf16 = 131072 B
  float* partials = (float*)(ws + 131072);      // 1024 floats

  negprep_k<<<32, 256, 0, stream>>>(tail_table, neg_idx, nws);
  keg_main<<<1024, 256, 0, stream>>>(head_table, tail_table, rel_vec, rel_bias,
                                     head_idx, tail_idx, (const u32x4*)nws, partials);
  reduce_k<<<1, 256, 0, stream>>>(partials, out);
}